// Round 9
// baseline (399.004 us; speedup 1.0000x reference)
//
#include <hip/hip_runtime.h>
#include <hip/hip_bf16.h>

#define H 16
#define F_IN 58
#define NPB 16     // nodes per block in t0 (256 threads / 16 lanes)
#define SCH 4160   // max edges per stage chunk (LDS sort capacity)
#define ECAP 4096  // LDS edge-cache capacity in agg (64 nodes * avg 32 = 2048 typ)

static inline size_t align256(size_t x) { return (x + 255) & ~(size_t)255; }

__device__ inline float bfu(unsigned short u) {
    return __uint_as_float(((unsigned)u) << 16);
}
__device__ inline unsigned packbf(float a, float b) {
    unsigned ua = (unsigned)__bfloat16_as_ushort(__float2bfloat16(a));
    unsigned ub = (unsigned)__bfloat16_as_ushort(__float2bfloat16(b));
    return ua | (ub << 16);
}

// ---------- dtype detection: int64 vs int32 edge_index ----------
__global__ void detect_kernel(const int* eidx32, int* flag) {
    __shared__ int any;
    if (threadIdx.x == 0) any = 0;
    __syncthreads();
    int nz = 0;
    for (int j = threadIdx.x; j < 1024; j += 256)
        nz |= (eidx32[2 * j + 1] != 0);
    if (nz) atomicOr(&any, 1);
    __syncthreads();
    if (threadIdx.x == 0) *flag = (any == 0) ? 1 : 0;  // all-zero odd words -> int64
}

__device__ inline int load_idx(const void* eidx, long i, int is64) {
    if (is64) return (int)((const long long*)eidx)[i];
    return ((const int*)eidx)[i];
}

// ---------- bucket counts (391 bins of 256 nodes) via LDS histogram ----------
__global__ void bcount_kernel(const void* eidx, int E, const int* flag64,
                              int n, int* bucketcnt) {
    __shared__ int hist[512];
    int is64 = *flag64;
    int B = (n + 255) >> 8;
    int tid = threadIdx.x;
    for (int j = tid; j < B; j += 256) hist[j] = 0;
    __syncthreads();
    int stride = gridDim.x * blockDim.x;
    for (int i = blockIdx.x * blockDim.x + tid; i < E; i += stride) {
        int d = load_idx(eidx, (long)E + i, is64);
        atomicAdd(&hist[d >> 8], 1);
    }
    __syncthreads();
    for (int j = tid; j < B; j += 256)
        if (hist[j]) atomicAdd(&bucketcnt[j], hist[j]);
}

// ---------- exclusive scan of bucket counts (single block, B <= 512) ----------
__global__ void bscan_kernel(const int* bucketcnt, int B, int E,
                             int* gcur, int* bucketbase) {
    __shared__ int tmp[512];
    int tid = threadIdx.x;
    int val = (tid < B) ? bucketcnt[tid] : 0;
    tmp[tid] = val;
    __syncthreads();
    for (int off = 1; off < 512; off <<= 1) {
        int t = (tid >= off) ? tmp[tid - off] : 0;
        __syncthreads();
        tmp[tid] += t;
        __syncthreads();
    }
    if (tid < B) {
        int ex = tmp[tid] - val;
        gcur[tid] = ex;
        bucketbase[tid] = ex;
    }
    if (tid == 0) bucketbase[B] = E;
}

// ---------- stage: LDS counting-sort each chunk by bucket, write coalesced runs ----------
__global__ void stage_kernel(const void* eidx, int E, const int* flag64,
                             int n, int* gcur, unsigned* staging) {
    __shared__ unsigned sorted[SCH];
    __shared__ unsigned short sbuck[SCH];
    __shared__ int hist[512];
    __shared__ int hbase[512];
    __shared__ int lofs[512];
    __shared__ int cursor[512];
    __shared__ int ps[256];

    int is64 = *flag64;
    int tid = threadIdx.x;
    int chunk = (E + gridDim.x - 1) / gridDim.x;
    int s0 = blockIdx.x * chunk;
    int s1 = min(E, s0 + chunk);
    int c = s1 - s0;
    if (c <= 0) return;

    for (int j = tid; j < 512; j += 256) { hist[j] = 0; cursor[j] = 0; }
    __syncthreads();

    // pass A: per-chunk bucket histogram
    for (int i = s0 + tid; i < s1; i += 256) {
        int d = load_idx(eidx, (long)E + i, is64);
        atomicAdd(&hist[d >> 8], 1);
    }
    __syncthreads();

    // pass B: reserve global run per bucket
    for (int j = tid; j < 512; j += 256) {
        int cc = hist[j];
        hbase[j] = cc ? atomicAdd(&gcur[j], cc) : 0;
    }

    // pass C: exclusive scan of hist -> lofs (512 bins, 256 threads)
    int a0 = hist[2 * tid], a1 = hist[2 * tid + 1];
    ps[tid] = a0 + a1;
    __syncthreads();
    for (int off = 1; off < 256; off <<= 1) {
        int t = (tid >= off) ? ps[tid - off] : 0;
        __syncthreads();
        ps[tid] += t;
        __syncthreads();
    }
    int ex = ps[tid] - (a0 + a1);
    lofs[2 * tid] = ex;
    lofs[2 * tid + 1] = ex + a0;
    __syncthreads();

    // pass D: scatter into LDS in bucket-sorted order
    for (int i = s0 + tid; i < s1; i += 256) {
        int s = load_idx(eidx, i, is64);
        int d = load_idx(eidx, (long)E + i, is64);
        int b = d >> 8;
        int loc = lofs[b] + atomicAdd(&cursor[b], 1);
        sorted[loc] = (unsigned)s | ((unsigned)(d & 255) << 17);
        sbuck[loc] = (unsigned short)b;
    }
    __syncthreads();

    // pass E: linear LDS read, coalesced run writes to global
    for (int i = tid; i < c; i += 256) {
        int b = sbuck[i];
        staging[hbase[b] + (i - lofs[b])] = sorted[i];
    }
}

// ---------- per-bucket local hist + scan -> rowstart/dinv, node-sorted ed ----------
__global__ void fine_kernel(const unsigned* __restrict__ staging,
                            const int* __restrict__ bucketbase, int n, int E,
                            int* __restrict__ ed, int* __restrict__ rowstart,
                            float* __restrict__ dinv) {
    __shared__ int lcnt[256];
    __shared__ int lofs[256];
    __shared__ int lcur[256];
    int tid = threadIdx.x;
    int b = blockIdx.x;
    int node0 = b << 8;
    int start = bucketbase[b], end = bucketbase[b + 1];
    int cnt = end - start;
    lcnt[tid] = 0;
    lcur[tid] = 0;
    __syncthreads();
    for (int i = tid; i < cnt; i += 256) {
        unsigned w = staging[start + i];
        atomicAdd(&lcnt[w >> 17], 1);
    }
    __syncthreads();
    int val = lcnt[tid];
    lofs[tid] = val;
    __syncthreads();
    for (int off = 1; off < 256; off <<= 1) {
        int t = (tid >= off) ? lofs[tid - off] : 0;
        __syncthreads();
        lofs[tid] += t;
        __syncthreads();
    }
    int ex = lofs[tid] - val;
    __syncthreads();
    lofs[tid] = ex;
    __syncthreads();
    int node = node0 + tid;
    if (node < n) {
        rowstart[node] = start + ex;
        dinv[node] = rsqrtf((float)(val + 1));
    }
    if (node == 0) rowstart[n] = E;
    for (int i = tid; i < cnt; i += 256) {
        unsigned w = staging[start + i];
        int ld = (int)(w >> 17);
        int pos = start + lofs[ld] + atomicAdd(&lcur[ld], 1);
        ed[pos] = (int)(w & 0x1FFFFu);
    }
}

// ---------- layer 0 dense transform: hw0 = bf16(dinv * (x @ W0)) ----------
__global__ void t0_kernel(const float* __restrict__ x, const float* __restrict__ W0,
                          const float* __restrict__ dinv,
                          unsigned short* __restrict__ hw, int n) {
    __shared__ float Wl[F_IN * H];
    int tid = threadIdx.x;
    for (int j = tid; j < F_IN * H; j += 256) Wl[j] = W0[j];
    __syncthreads();
    int g = tid >> 4, f = tid & 15;
    int v = blockIdx.x * NPB + g;
    if (v >= n) return;
    const float* xr = x + (long)v * F_IN;
    float acc = 0.f;
#pragma unroll
    for (int k = 0; k < F_IN; ++k) acc += xr[k] * Wl[k * H + f];
    hw[v * H + f] = __bfloat16_as_ushort(__float2bfloat16(acc * dinv[v]));
}

// ---------- aggregation: 64 nodes/block, 4 lanes/node (one feature-quad each) ----------
// 16-deep gather pipeline; hw gathers temporal (L2), all streams non-temporal.
// hw holds dinv-scaled features (bf16); agg = dinv[v]*(sum_src hw[src] + hw[v])
#define LD8(U, T) ushort4 U = *(const ushort4*)(hw + (T) * H + fb)
#define AC4(A0, A1, A2, A3, U) \
    A0 += bfu(U.x); A1 += bfu(U.y); A2 += bfu(U.z); A3 += bfu(U.w)

__global__ __launch_bounds__(256) void agg_kernel(
    const int* __restrict__ ed, const int* __restrict__ rowstart,
    const float* __restrict__ dinv, const unsigned short* __restrict__ hw,
    const float* __restrict__ bias, const float* __restrict__ Wnext,
    unsigned short* __restrict__ jk, unsigned short* __restrict__ hw_next,
    int n, int first, int has_next) {
    __shared__ float Wl[H * H];
    __shared__ int eds[ECAP];
    __shared__ int rs[65];
    int tid = threadIdx.x;
    if (has_next) Wl[tid] = Wnext[tid];  // 256 threads == 16x16
    int node0 = blockIdx.x * 64;
    int nn = min(64, n - node0);         // nodes in this block (>=1)
    if (tid <= nn) rs[tid] = rowstart[node0 + tid];
    __syncthreads();
    int s0 = rs[0];
    int cnt = rs[nn] - s0;
    for (int i = tid; i < cnt && i < ECAP; i += 256)
        eds[i] = __builtin_nontemporal_load(&ed[s0 + i]);
    __syncthreads();

    int g = tid >> 2, l = tid & 3;       // 64 nodes/block, 4 lanes/node
    if (g >= nn) return;
    int v = node0 + g;
    int fb = l * 4;                      // this lane's feature quad

    float a0 = 0.f, a1 = 0.f, a2 = 0.f, a3 = 0.f;
    float c0 = 0.f, c1 = 0.f, c2 = 0.f, c3 = 0.f;
    int ls = rs[g] - s0, le = rs[g + 1] - s0;
    int i = ls;

    if (le <= ECAP) {                    // fast path: indices from LDS
        for (; i + 16 <= le; i += 16) {
            int t0 = eds[i],      t1 = eds[i + 1],  t2 = eds[i + 2],  t3 = eds[i + 3];
            int t4 = eds[i + 4],  t5 = eds[i + 5],  t6 = eds[i + 6],  t7 = eds[i + 7];
            int t8 = eds[i + 8],  t9 = eds[i + 9],  ta = eds[i + 10], tb = eds[i + 11];
            int tc = eds[i + 12], td = eds[i + 13], te = eds[i + 14], tf = eds[i + 15];
            LD8(u0, t0); LD8(u1, t1); LD8(u2, t2); LD8(u3, t3);
            LD8(u4, t4); LD8(u5, t5); LD8(u6, t6); LD8(u7, t7);
            LD8(u8, t8); LD8(u9, t9); LD8(ua, ta); LD8(ub, tb);
            LD8(uc, tc); LD8(ud, td); LD8(ue, te); LD8(uf, tf);
            AC4(a0, a1, a2, a3, u0); AC4(c0, c1, c2, c3, u1);
            AC4(a0, a1, a2, a3, u2); AC4(c0, c1, c2, c3, u3);
            AC4(a0, a1, a2, a3, u4); AC4(c0, c1, c2, c3, u5);
            AC4(a0, a1, a2, a3, u6); AC4(c0, c1, c2, c3, u7);
            AC4(a0, a1, a2, a3, u8); AC4(c0, c1, c2, c3, u9);
            AC4(a0, a1, a2, a3, ua); AC4(c0, c1, c2, c3, ub);
            AC4(a0, a1, a2, a3, uc); AC4(c0, c1, c2, c3, ud);
            AC4(a0, a1, a2, a3, ue); AC4(c0, c1, c2, c3, uf);
        }
        for (; i + 4 <= le; i += 4) {
            int t0 = eds[i], t1 = eds[i + 1], t2 = eds[i + 2], t3 = eds[i + 3];
            LD8(u0, t0); LD8(u1, t1); LD8(u2, t2); LD8(u3, t3);
            AC4(a0, a1, a2, a3, u0); AC4(c0, c1, c2, c3, u1);
            AC4(a0, a1, a2, a3, u2); AC4(c0, c1, c2, c3, u3);
        }
        for (; i < le; ++i) {
            LD8(u0, eds[i]);
            AC4(a0, a1, a2, a3, u0);
        }
    } else {                             // fallback: indices from global (huge block)
        for (; i + 4 <= le; i += 4) {
            int t0 = __builtin_nontemporal_load(&ed[s0 + i]);
            int t1 = __builtin_nontemporal_load(&ed[s0 + i + 1]);
            int t2 = __builtin_nontemporal_load(&ed[s0 + i + 2]);
            int t3 = __builtin_nontemporal_load(&ed[s0 + i + 3]);
            LD8(u0, t0); LD8(u1, t1); LD8(u2, t2); LD8(u3, t3);
            AC4(a0, a1, a2, a3, u0); AC4(c0, c1, c2, c3, u1);
            AC4(a0, a1, a2, a3, u2); AC4(c0, c1, c2, c3, u3);
        }
        for (; i < le; ++i) {
            int t0 = __builtin_nontemporal_load(&ed[s0 + i]);
            LD8(u0, t0);
            AC4(a0, a1, a2, a3, u0);
        }
    }

    // self-loop + bias + relu
    ushort4 us = *(const ushort4*)(hw + (size_t)v * H + fb);
    float dv = dinv[v];
    float4 bv = *(const float4*)(bias + fb);
    float v0 = fmaxf((a0 + c0 + bfu(us.x)) * dv + bv.x, 0.f);
    float v1 = fmaxf((a1 + c1 + bfu(us.y)) * dv + bv.y, 0.f);
    float v2 = fmaxf((a2 + c2 + bfu(us.z)) * dv + bv.z, 0.f);
    float v3 = fmaxf((a3 + c3 + bfu(us.w)) * dv + bv.w, 0.f);

    // jk running max in bf16 (each lane owns its 8B quad; 4 lanes = 32B row)
    {
        unsigned long long* jkp =
            (unsigned long long*)(jk + (size_t)v * H + fb);
        float m0 = v0, m1 = v1, m2 = v2, m3 = v3;
        if (!first) {
            unsigned long long jo = __builtin_nontemporal_load(jkp);
            m0 = fmaxf(m0, bfu((unsigned short)jo));
            m1 = fmaxf(m1, bfu((unsigned short)(jo >> 16)));
            m2 = fmaxf(m2, bfu((unsigned short)(jo >> 32)));
            m3 = fmaxf(m3, bfu((unsigned short)(jo >> 48)));
        }
        unsigned long long st = (unsigned long long)packbf(m0, m1)
                              | ((unsigned long long)packbf(m2, m3) << 32);
        __builtin_nontemporal_store(st, jkp);
    }

    // fused next-layer transform: out[f'] = sum_k val_all[k] * W[k][f']
    if (has_next) {
        float4 o = make_float4(0.f, 0.f, 0.f, 0.f);
#pragma unroll
        for (int kq = 0; kq < 4; ++kq) {
            float4 vk;
            vk.x = __shfl(v0, kq, 4);
            vk.y = __shfl(v1, kq, 4);
            vk.z = __shfl(v2, kq, 4);
            vk.w = __shfl(v3, kq, 4);
            float4 w0 = *(const float4*)(Wl + (4 * kq + 0) * H + fb);
            float4 w1 = *(const float4*)(Wl + (4 * kq + 1) * H + fb);
            float4 w2 = *(const float4*)(Wl + (4 * kq + 2) * H + fb);
            float4 w3 = *(const float4*)(Wl + (4 * kq + 3) * H + fb);
            o.x += vk.x * w0.x + vk.y * w1.x + vk.z * w2.x + vk.w * w3.x;
            o.y += vk.x * w0.y + vk.y * w1.y + vk.z * w2.y + vk.w * w3.y;
            o.z += vk.x * w0.z + vk.y * w1.z + vk.z * w2.z + vk.w * w3.z;
            o.w += vk.x * w0.w + vk.y * w1.w + vk.z * w2.w + vk.w * w3.w;
        }
        uint2 st;
        st.x = packbf(o.x * dv, o.y * dv);
        st.y = packbf(o.z * dv, o.w * dv);
        *(uint2*)(hw_next + (size_t)v * H + fb) = st;  // temporal: next layer's gather target
    }
}

// ---------- final FC: out = jk @ fc_w + fc_b (jk in bf16) ----------
__global__ void fc_kernel(const unsigned short* __restrict__ jk,
                          const float* __restrict__ fc_w,
                          const float* __restrict__ fc_b, float* __restrict__ out, int n) {
    __shared__ float w[H];
    __shared__ float b0;
    if (threadIdx.x < H) w[threadIdx.x] = fc_w[threadIdx.x];
    if (threadIdx.x == 0) b0 = fc_b[0];
    __syncthreads();
    int v = blockIdx.x * 256 + threadIdx.x;
    if (v >= n) return;
    const uint4* r = (const uint4*)(jk + (size_t)v * H);
    uint4 a = r[0], b = r[1];
    float sum = bfu((unsigned short)a.x) * w[0]  + bfu((unsigned short)(a.x >> 16)) * w[1]
              + bfu((unsigned short)a.y) * w[2]  + bfu((unsigned short)(a.y >> 16)) * w[3]
              + bfu((unsigned short)a.z) * w[4]  + bfu((unsigned short)(a.z >> 16)) * w[5]
              + bfu((unsigned short)a.w) * w[6]  + bfu((unsigned short)(a.w >> 16)) * w[7]
              + bfu((unsigned short)b.x) * w[8]  + bfu((unsigned short)(b.x >> 16)) * w[9]
              + bfu((unsigned short)b.y) * w[10] + bfu((unsigned short)(b.y >> 16)) * w[11]
              + bfu((unsigned short)b.z) * w[12] + bfu((unsigned short)(b.z >> 16)) * w[13]
              + bfu((unsigned short)b.w) * w[14] + bfu((unsigned short)(b.w >> 16)) * w[15];
    out[v] = sum + b0;
}

extern "C" void kernel_launch(void* const* d_in, const int* in_sizes, int n_in,
                              void* d_out, int out_size, void* d_ws, size_t ws_size,
                              hipStream_t stream) {
    const float* x    = (const float*)d_in[0];
    const void*  eidx = d_in[1];
    const float* W0   = (const float*)d_in[2];
    const float* Ws   = (const float*)d_in[3];
    const float* bs   = (const float*)d_in[4];
    const float* fc_w = (const float*)d_in[5];
    const float* fc_b = (const float*)d_in[6];

    int n = in_sizes[0] / F_IN;        // 100000
    int E = in_sizes[1] / 2;           // 3200000
    int L = in_sizes[4] / H;           // 10

    // workspace carve-up
    char* w = (char*)d_ws;
    size_t off = 0;
    int* rowstart    = (int*)(w + off); off += align256((size_t)(n + 1) * 4);
    float* dinv      = (float*)(w + off); off += align256((size_t)n * 4);
    int* bucketcnt   = (int*)(w + off); off += align256(512 * 4);
    int* bucketbase  = (int*)(w + off); off += align256(513 * 4);
    int* gcur        = (int*)(w + off); off += align256(512 * 4);
    int* flag64      = (int*)(w + off); off += align256(256);
    unsigned* stg    = (unsigned*)(w + off); off += align256((size_t)E * 4);
    int* ed          = (int*)(w + off); off += align256((size_t)E * 4);
    unsigned short* hwA = (unsigned short*)(w + off); off += align256((size_t)n * H * 2);
    unsigned short* hwB = (unsigned short*)(w + off); off += align256((size_t)n * H * 2);
    unsigned short* jk  = (unsigned short*)(w + off); off += align256((size_t)n * H * 2);

    int NB = (n + 255) / 256;          // 391 buckets of 256 nodes

    hipMemsetAsync(bucketcnt, 0, 512 * 4, stream);
    detect_kernel<<<1, 256, 0, stream>>>((const int*)eidx, flag64);
    bcount_kernel<<<512, 256, 0, stream>>>(eidx, E, flag64, n, bucketcnt);
    bscan_kernel<<<1, 512, 0, stream>>>(bucketcnt, NB, E, gcur, bucketbase);
    int SG = (E + 4095) / 4096;        // chunk <= 4096 <= SCH
    stage_kernel<<<SG, 256, 0, stream>>>(eidx, E, flag64, n, gcur, stg);
    fine_kernel<<<NB, 256, 0, stream>>>(stg, bucketbase, n, E, ed, rowstart, dinv);

    int ngrid = (n + NPB - 1) / NPB;   // 6250
    t0_kernel<<<ngrid, 256, 0, stream>>>(x, W0, dinv, hwA, n);

    unsigned short* cur = hwA;
    unsigned short* nxt = hwB;
    int agrid = (n + 63) / 64;         // 1563
    for (int l = 0; l < L; ++l) {
        const float* bias  = bs + (size_t)l * H;
        const float* Wnext = (l < L - 1) ? (Ws + (size_t)l * H * H) : nullptr;
        agg_kernel<<<agrid, 256, 0, stream>>>(ed, rowstart, dinv, cur, bias, Wnext,
                                              jk, nxt, n, (l == 0) ? 1 : 0,
                                              (l < L - 1) ? 1 : 0);
        unsigned short* t = cur; cur = nxt; nxt = t;
    }

    fc_kernel<<<NB, 256, 0, stream>>>(jk, fc_w, fc_b, (float*)d_out, n);
}

// Round 10
// 382.856 us; speedup vs baseline: 1.0422x; 1.0422x over previous
//
#include <hip/hip_runtime.h>
#include <hip/hip_bf16.h>

#define H 16
#define F_IN 58
#define NPB 16     // nodes per block in t0 (256 threads / 16 lanes)
#define SCH 2048   // max edges per stage chunk (LDS sort capacity)
#define ECAP 4096  // LDS edge-cache capacity in agg (64 nodes * avg 32 = 2048 typ)

static inline size_t align256(size_t x) { return (x + 255) & ~(size_t)255; }

__device__ inline float bf2f(__hip_bfloat16 h) { return __bfloat162float(h); }
__device__ inline float bfu2f(unsigned short u) {
    return __uint_as_float(((unsigned)u) << 16);
}

// ---------- dtype detection: int64 vs int32 edge_index ----------
__global__ void detect_kernel(const int* eidx32, int* flag) {
    __shared__ int any;
    if (threadIdx.x == 0) any = 0;
    __syncthreads();
    int nz = 0;
    for (int j = threadIdx.x; j < 1024; j += 256)
        nz |= (eidx32[2 * j + 1] != 0);
    if (nz) atomicOr(&any, 1);
    __syncthreads();
    if (threadIdx.x == 0) *flag = (any == 0) ? 1 : 0;  // all-zero odd words -> int64
}

__device__ inline int load_idx(const void* eidx, long i, int is64) {
    if (is64) return (int)((const long long*)eidx)[i];
    return ((const int*)eidx)[i];
}

// ---------- bucket counts (391 bins of 256 nodes) via LDS histogram ----------
__global__ void bcount_kernel(const void* eidx, int E, const int* flag64,
                              int n, int* bucketcnt) {
    __shared__ int hist[512];
    int is64 = *flag64;
    int B = (n + 255) >> 8;
    int tid = threadIdx.x;
    for (int j = tid; j < B; j += 256) hist[j] = 0;
    __syncthreads();
    int stride = gridDim.x * blockDim.x;
    for (int i = blockIdx.x * blockDim.x + tid; i < E; i += stride) {
        int d = load_idx(eidx, (long)E + i, is64);
        atomicAdd(&hist[d >> 8], 1);
    }
    __syncthreads();
    for (int j = tid; j < B; j += 256)
        if (hist[j]) atomicAdd(&bucketcnt[j], hist[j]);
}

// ---------- exclusive scan of bucket counts (single block, B <= 512) ----------
__global__ void bscan_kernel(const int* bucketcnt, int B, int E,
                             int* gcur, int* bucketbase) {
    __shared__ int tmp[512];
    int tid = threadIdx.x;
    int val = (tid < B) ? bucketcnt[tid] : 0;
    tmp[tid] = val;
    __syncthreads();
    for (int off = 1; off < 512; off <<= 1) {
        int t = (tid >= off) ? tmp[tid - off] : 0;
        __syncthreads();
        tmp[tid] += t;
        __syncthreads();
    }
    if (tid < B) {
        int ex = tmp[tid] - val;
        gcur[tid] = ex;
        bucketbase[tid] = ex;
    }
    if (tid == 0) bucketbase[B] = E;
}

// ---------- stage: LDS counting-sort each chunk by bucket, write coalesced runs ----------
__global__ void stage_kernel(const void* eidx, int E, const int* flag64,
                             int n, int* gcur, unsigned* staging) {
    __shared__ unsigned sorted[SCH];
    __shared__ unsigned short sbuck[SCH];
    __shared__ int hist[512];
    __shared__ int hbase[512];
    __shared__ int lofs[512];
    __shared__ int cursor[512];
    __shared__ int ps[256];

    int is64 = *flag64;
    int tid = threadIdx.x;
    int chunk = (E + gridDim.x - 1) / gridDim.x;
    int s0 = blockIdx.x * chunk;
    int s1 = min(E, s0 + chunk);
    int c = s1 - s0;
    if (c <= 0) return;

    for (int j = tid; j < 512; j += 256) { hist[j] = 0; cursor[j] = 0; }
    __syncthreads();

    // pass A: per-chunk bucket histogram
    for (int i = s0 + tid; i < s1; i += 256) {
        int d = load_idx(eidx, (long)E + i, is64);
        atomicAdd(&hist[d >> 8], 1);
    }
    __syncthreads();

    // pass B: reserve global run per bucket
    for (int j = tid; j < 512; j += 256) {
        int cc = hist[j];
        hbase[j] = cc ? atomicAdd(&gcur[j], cc) : 0;
    }

    // pass C: exclusive scan of hist -> lofs (512 bins, 256 threads)
    int a0 = hist[2 * tid], a1 = hist[2 * tid + 1];
    ps[tid] = a0 + a1;
    __syncthreads();
    for (int off = 1; off < 256; off <<= 1) {
        int t = (tid >= off) ? ps[tid - off] : 0;
        __syncthreads();
        ps[tid] += t;
        __syncthreads();
    }
    int ex = ps[tid] - (a0 + a1);
    lofs[2 * tid] = ex;
    lofs[2 * tid + 1] = ex + a0;
    __syncthreads();

    // pass D: scatter into LDS in bucket-sorted order
    for (int i = s0 + tid; i < s1; i += 256) {
        int s = load_idx(eidx, i, is64);
        int d = load_idx(eidx, (long)E + i, is64);
        int b = d >> 8;
        int loc = lofs[b] + atomicAdd(&cursor[b], 1);
        sorted[loc] = (unsigned)s | ((unsigned)(d & 255) << 17);
        sbuck[loc] = (unsigned short)b;
    }
    __syncthreads();

    // pass E: linear LDS read, coalesced run writes to global
    for (int i = tid; i < c; i += 256) {
        int b = sbuck[i];
        staging[hbase[b] + (i - lofs[b])] = sorted[i];
    }
}

// ---------- per-bucket local hist + scan -> rowstart/dinv/perm, node-sorted ed ----------
__global__ void fine_kernel(const unsigned* __restrict__ staging,
                            const int* __restrict__ bucketbase, int n, int E,
                            int* __restrict__ ed, int* __restrict__ rowstart,
                            float* __restrict__ dinv, int* __restrict__ perm) {
    __shared__ int lcnt[256];
    __shared__ int lofs[256];
    __shared__ int lcur[256];
    int tid = threadIdx.x;
    int b = blockIdx.x;
    int node0 = b << 8;
    int start = bucketbase[b], end = bucketbase[b + 1];
    int cnt = end - start;
    lcnt[tid] = 0;
    lcur[tid] = 0;
    __syncthreads();
    for (int i = tid; i < cnt; i += 256) {
        unsigned w = staging[start + i];
        atomicAdd(&lcnt[w >> 17], 1);
    }
    __syncthreads();
    int val = lcnt[tid];
    lofs[tid] = val;
    __syncthreads();
    for (int off = 1; off < 256; off <<= 1) {
        int t = (tid >= off) ? lofs[tid - off] : 0;
        __syncthreads();
        lofs[tid] += t;
        __syncthreads();
    }
    int ex = lofs[tid] - val;
    __syncthreads();
    lofs[tid] = ex;
    __syncthreads();
    int node = node0 + tid;
    if (node < n) {
        rowstart[node] = start + ex;
        dinv[node] = rsqrtf((float)(val + 1));
    }
    if (node == 0) rowstart[n] = E;

    // node-sorted edge scatter within bucket
    for (int i = tid; i < cnt; i += 256) {
        unsigned w = staging[start + i];
        int ld = (int)(w >> 17);
        int pos = start + lofs[ld] + atomicAdd(&lcur[ld], 1);
        ed[pos] = (int)(w & 0x1FFFFu);
    }

    // degree-sort each 64-node window -> perm (agg wave-balance).
    // Invalid nodes (>= n) rank last; deterministic tie-break by index.
    {
        int w = tid >> 6, j = tid & 63;
        int wbase = w * 64;
        int d = (node < n) ? lcnt[tid] : 0x7FFFFFFF;
        int rank = 0;
        for (int k = 0; k < 64; ++k) {
            int nk = node0 + wbase + k;
            int dk = (nk < n) ? lcnt[wbase + k] : 0x7FFFFFFF;
            rank += (dk < d) | ((dk == d) & (k < j));
        }
        if (node < n) perm[node0 + wbase + rank] = node;
    }
}

// ---------- layer 0 dense transform: hw0 = bf16(dinv * (x @ W0)) ----------
__global__ void t0_kernel(const float* __restrict__ x, const float* __restrict__ W0,
                          const float* __restrict__ dinv,
                          __hip_bfloat16* __restrict__ hw, int n) {
    __shared__ float Wl[F_IN * H];
    int tid = threadIdx.x;
    for (int j = tid; j < F_IN * H; j += 256) Wl[j] = W0[j];
    __syncthreads();
    int g = tid >> 4, f = tid & 15;
    int v = blockIdx.x * NPB + g;
    if (v >= n) return;
    const float* xr = x + (long)v * F_IN;
    float acc = 0.f;
#pragma unroll
    for (int k = 0; k < F_IN; ++k) acc += xr[k] * Wl[k * H + f];
    hw[v * H + f] = __float2bfloat16(acc * dinv[v]);
}

// ---------- aggregation: 64 nodes/block, 4 lanes/node x 4 features, LDS edge cache,
// degree-sorted node assignment via perm ----------
// hw holds dinv-scaled features (bf16); agg = dinv[v]*(sum_src hw[src] + hw[v])
__global__ __launch_bounds__(256) void agg_kernel(
    const int* __restrict__ ed, const int* __restrict__ rowstart,
    const int* __restrict__ perm,
    const float* __restrict__ dinv, const __hip_bfloat16* __restrict__ hw,
    const float* __restrict__ bias, const float* __restrict__ Wnext,
    float* __restrict__ jk, __hip_bfloat16* __restrict__ hw_next,
    int n, int first, int has_next) {
    __shared__ float Wl[H * H];
    __shared__ int eds[ECAP];
    __shared__ int rs[65];
    __shared__ int pm[64];
    int tid = threadIdx.x;
    if (has_next) Wl[tid] = Wnext[tid];  // 256 threads == 16x16
    int node0 = blockIdx.x * 64;
    int nn = min(64, n - node0);         // nodes in this block (>=1)
    if (tid <= nn) rs[tid] = rowstart[node0 + tid];
    if (tid < nn) pm[tid] = perm[node0 + tid];
    __syncthreads();
    int s0 = rs[0];
    int cnt = rs[nn] - s0;
    for (int i = tid; i < cnt && i < ECAP; i += 256) eds[i] = ed[s0 + i];
    __syncthreads();

    int g = tid >> 2, l = tid & 3;       // 64 nodes/block, 4 lanes/node
    if (g >= nn) return;
    int v = pm[g];                       // degree-sorted node
    int lv = v - node0;                  // local index into rs
    int fb = l * 4;                      // feature quad base
    const unsigned short* hwu = (const unsigned short*)hw;

    float4 accA = make_float4(0.f, 0.f, 0.f, 0.f);
    float4 accB = make_float4(0.f, 0.f, 0.f, 0.f);
    int ls = rs[lv] - s0, le = rs[lv + 1] - s0;

    if (le <= ECAP) {                    // fast path: indices from LDS
        int i = ls;
        for (; i + 8 <= le; i += 8) {
            int t0 = eds[i],     t1 = eds[i + 1], t2 = eds[i + 2], t3 = eds[i + 3];
            int t4 = eds[i + 4], t5 = eds[i + 5], t6 = eds[i + 6], t7 = eds[i + 7];
            ushort4 u0 = *(const ushort4*)(hwu + t0 * H + fb);
            ushort4 u1 = *(const ushort4*)(hwu + t1 * H + fb);
            ushort4 u2 = *(const ushort4*)(hwu + t2 * H + fb);
            ushort4 u3 = *(const ushort4*)(hwu + t3 * H + fb);
            ushort4 u4 = *(const ushort4*)(hwu + t4 * H + fb);
            ushort4 u5 = *(const ushort4*)(hwu + t5 * H + fb);
            ushort4 u6 = *(const ushort4*)(hwu + t6 * H + fb);
            ushort4 u7 = *(const ushort4*)(hwu + t7 * H + fb);
            accA.x += bfu2f(u0.x); accA.y += bfu2f(u0.y); accA.z += bfu2f(u0.z); accA.w += bfu2f(u0.w);
            accB.x += bfu2f(u1.x); accB.y += bfu2f(u1.y); accB.z += bfu2f(u1.z); accB.w += bfu2f(u1.w);
            accA.x += bfu2f(u2.x); accA.y += bfu2f(u2.y); accA.z += bfu2f(u2.z); accA.w += bfu2f(u2.w);
            accB.x += bfu2f(u3.x); accB.y += bfu2f(u3.y); accB.z += bfu2f(u3.z); accB.w += bfu2f(u3.w);
            accA.x += bfu2f(u4.x); accA.y += bfu2f(u4.y); accA.z += bfu2f(u4.z); accA.w += bfu2f(u4.w);
            accB.x += bfu2f(u5.x); accB.y += bfu2f(u5.y); accB.z += bfu2f(u5.z); accB.w += bfu2f(u5.w);
            accA.x += bfu2f(u6.x); accA.y += bfu2f(u6.y); accA.z += bfu2f(u6.z); accA.w += bfu2f(u6.w);
            accB.x += bfu2f(u7.x); accB.y += bfu2f(u7.y); accB.z += bfu2f(u7.z); accB.w += bfu2f(u7.w);
        }
        for (; i < le; ++i) {
            ushort4 u = *(const ushort4*)(hwu + eds[i] * H + fb);
            accA.x += bfu2f(u.x); accA.y += bfu2f(u.y); accA.z += bfu2f(u.z); accA.w += bfu2f(u.w);
        }
    } else {                             // fallback: indices from global (huge block)
        int i = s0 + ls, e = s0 + le;
        for (; i + 8 <= e; i += 8) {
            int t0 = ed[i],     t1 = ed[i + 1], t2 = ed[i + 2], t3 = ed[i + 3];
            int t4 = ed[i + 4], t5 = ed[i + 5], t6 = ed[i + 6], t7 = ed[i + 7];
            ushort4 u0 = *(const ushort4*)(hwu + t0 * H + fb);
            ushort4 u1 = *(const ushort4*)(hwu + t1 * H + fb);
            ushort4 u2 = *(const ushort4*)(hwu + t2 * H + fb);
            ushort4 u3 = *(const ushort4*)(hwu + t3 * H + fb);
            ushort4 u4 = *(const ushort4*)(hwu + t4 * H + fb);
            ushort4 u5 = *(const ushort4*)(hwu + t5 * H + fb);
            ushort4 u6 = *(const ushort4*)(hwu + t6 * H + fb);
            ushort4 u7 = *(const ushort4*)(hwu + t7 * H + fb);
            accA.x += bfu2f(u0.x); accA.y += bfu2f(u0.y); accA.z += bfu2f(u0.z); accA.w += bfu2f(u0.w);
            accB.x += bfu2f(u1.x); accB.y += bfu2f(u1.y); accB.z += bfu2f(u1.z); accB.w += bfu2f(u1.w);
            accA.x += bfu2f(u2.x); accA.y += bfu2f(u2.y); accA.z += bfu2f(u2.z); accA.w += bfu2f(u2.w);
            accB.x += bfu2f(u3.x); accB.y += bfu2f(u3.y); accB.z += bfu2f(u3.z); accB.w += bfu2f(u3.w);
            accA.x += bfu2f(u4.x); accA.y += bfu2f(u4.y); accA.z += bfu2f(u4.z); accA.w += bfu2f(u4.w);
            accB.x += bfu2f(u5.x); accB.y += bfu2f(u5.y); accB.z += bfu2f(u5.z); accB.w += bfu2f(u5.w);
            accA.x += bfu2f(u6.x); accA.y += bfu2f(u6.y); accA.z += bfu2f(u6.z); accA.w += bfu2f(u6.w);
            accB.x += bfu2f(u7.x); accB.y += bfu2f(u7.y); accB.z += bfu2f(u7.z); accB.w += bfu2f(u7.w);
        }
        for (; i < e; ++i) {
            ushort4 u = *(const ushort4*)(hwu + ed[i] * H + fb);
            accA.x += bfu2f(u.x); accA.y += bfu2f(u.y); accA.z += bfu2f(u.z); accA.w += bfu2f(u.w);
        }
    }

    // self-loop + bias + relu
    ushort4 us = *(const ushort4*)(hwu + (size_t)v * H + fb);
    float dv = dinv[v];
    float4 bv = *(const float4*)(bias + fb);
    float4 val;
    val.x = fmaxf((accA.x + accB.x + bfu2f(us.x)) * dv + bv.x, 0.f);
    val.y = fmaxf((accA.y + accB.y + bfu2f(us.y)) * dv + bv.y, 0.f);
    val.z = fmaxf((accA.z + accB.z + bfu2f(us.z)) * dv + bv.z, 0.f);
    val.w = fmaxf((accA.w + accB.w + bfu2f(us.w)) * dv + bv.w, 0.f);

    // jk running max (float4 per lane)
    float4* jkp = (float4*)(jk + (size_t)v * H + fb);
    float4 jv = val;
    if (!first) {
        float4 jo = *jkp;
        jv.x = fmaxf(jo.x, val.x); jv.y = fmaxf(jo.y, val.y);
        jv.z = fmaxf(jo.z, val.z); jv.w = fmaxf(jo.w, val.w);
    }
    *jkp = jv;

    // fused next-layer transform: out[f'] = sum_k val_all[k] * W[k][f']
    if (has_next) {
        float4 o = make_float4(0.f, 0.f, 0.f, 0.f);
#pragma unroll
        for (int kq = 0; kq < 4; ++kq) {
            float4 vk;
            vk.x = __shfl(val.x, kq, 4);
            vk.y = __shfl(val.y, kq, 4);
            vk.z = __shfl(val.z, kq, 4);
            vk.w = __shfl(val.w, kq, 4);
            float4 w0 = *(const float4*)(Wl + (4 * kq + 0) * H + fb);
            float4 w1 = *(const float4*)(Wl + (4 * kq + 1) * H + fb);
            float4 w2 = *(const float4*)(Wl + (4 * kq + 2) * H + fb);
            float4 w3 = *(const float4*)(Wl + (4 * kq + 3) * H + fb);
            o.x += vk.x * w0.x + vk.y * w1.x + vk.z * w2.x + vk.w * w3.x;
            o.y += vk.x * w0.y + vk.y * w1.y + vk.z * w2.y + vk.w * w3.y;
            o.z += vk.x * w0.z + vk.y * w1.z + vk.z * w2.z + vk.w * w3.z;
            o.w += vk.x * w0.w + vk.y * w1.w + vk.z * w2.w + vk.w * w3.w;
        }
        ushort4 ob;
        ob.x = (unsigned short)(__bfloat16_as_ushort(__float2bfloat16(o.x * dv)));
        ob.y = (unsigned short)(__bfloat16_as_ushort(__float2bfloat16(o.y * dv)));
        ob.z = (unsigned short)(__bfloat16_as_ushort(__float2bfloat16(o.z * dv)));
        ob.w = (unsigned short)(__bfloat16_as_ushort(__float2bfloat16(o.w * dv)));
        *(ushort4*)((unsigned short*)hw_next + (size_t)v * H + fb) = ob;
    }
}

// ---------- final FC: out = jk @ fc_w + fc_b ----------
__global__ void fc_kernel(const float* __restrict__ jk, const float* __restrict__ fc_w,
                          const float* __restrict__ fc_b, float* __restrict__ out, int n) {
    __shared__ float w[H];
    __shared__ float b0;
    if (threadIdx.x < H) w[threadIdx.x] = fc_w[threadIdx.x];
    if (threadIdx.x == 0) b0 = fc_b[0];
    __syncthreads();
    int v = blockIdx.x * 256 + threadIdx.x;
    if (v >= n) return;
    const float4* r = (const float4*)(jk + (long)v * H);
    float4 a = r[0], b = r[1], c = r[2], d = r[3];
    float sum = a.x * w[0] + a.y * w[1] + a.z * w[2] + a.w * w[3]
              + b.x * w[4] + b.y * w[5] + b.z * w[6] + b.w * w[7]
              + c.x * w[8] + c.y * w[9] + c.z * w[10] + c.w * w[11]
              + d.x * w[12] + d.y * w[13] + d.z * w[14] + d.w * w[15];
    out[v] = sum + b0;
}

extern "C" void kernel_launch(void* const* d_in, const int* in_sizes, int n_in,
                              void* d_out, int out_size, void* d_ws, size_t ws_size,
                              hipStream_t stream) {
    const float* x    = (const float*)d_in[0];
    const void*  eidx = d_in[1];
    const float* W0   = (const float*)d_in[2];
    const float* Ws   = (const float*)d_in[3];
    const float* bs   = (const float*)d_in[4];
    const float* fc_w = (const float*)d_in[5];
    const float* fc_b = (const float*)d_in[6];

    int n = in_sizes[0] / F_IN;        // 100000
    int E = in_sizes[1] / 2;           // 3200000
    int L = in_sizes[4] / H;           // 10

    // workspace carve-up
    char* w = (char*)d_ws;
    size_t off = 0;
    int* rowstart    = (int*)(w + off); off += align256((size_t)(n + 1) * 4);
    float* dinv      = (float*)(w + off); off += align256((size_t)n * 4);
    int* perm        = (int*)(w + off); off += align256((size_t)(n + 256) * 4);
    int* bucketcnt   = (int*)(w + off); off += align256(512 * 4);
    int* bucketbase  = (int*)(w + off); off += align256(513 * 4);
    int* gcur        = (int*)(w + off); off += align256(512 * 4);
    int* flag64      = (int*)(w + off); off += align256(256);
    unsigned* stg    = (unsigned*)(w + off); off += align256((size_t)E * 4);
    int* ed          = (int*)(w + off); off += align256((size_t)E * 4);
    __hip_bfloat16* hwA = (__hip_bfloat16*)(w + off); off += align256((size_t)n * H * 2);
    __hip_bfloat16* hwB = (__hip_bfloat16*)(w + off); off += align256((size_t)n * H * 2);
    float* jk        = (float*)(w + off); off += align256((size_t)n * H * 4);

    int NB = (n + 255) / 256;          // 391 buckets of 256 nodes

    hipMemsetAsync(bucketcnt, 0, 512 * 4, stream);
    detect_kernel<<<1, 256, 0, stream>>>((const int*)eidx, flag64);
    bcount_kernel<<<512, 256, 0, stream>>>(eidx, E, flag64, n, bucketcnt);
    bscan_kernel<<<1, 512, 0, stream>>>(bucketcnt, NB, E, gcur, bucketbase);
    int SG = (E + 2047) / 2048;        // chunk <= 2048 == SCH
    stage_kernel<<<SG, 256, 0, stream>>>(eidx, E, flag64, n, gcur, stg);
    fine_kernel<<<NB, 256, 0, stream>>>(stg, bucketbase, n, E, ed, rowstart, dinv, perm);

    int ngrid = (n + NPB - 1) / NPB;   // 6250
    t0_kernel<<<ngrid, 256, 0, stream>>>(x, W0, dinv, hwA, n);

    __hip_bfloat16* cur = hwA;
    __hip_bfloat16* nxt = hwB;
    int agrid = (n + 63) / 64;         // 1563
    for (int l = 0; l < L; ++l) {
        const float* bias  = bs + (size_t)l * H;
        const float* Wnext = (l < L - 1) ? (Ws + (size_t)l * H * H) : nullptr;
        agg_kernel<<<agrid, 256, 0, stream>>>(ed, rowstart, perm, dinv, cur, bias, Wnext,
                                              jk, nxt, n, (l == 0) ? 1 : 0,
                                              (l < L - 1) ? 1 : 0);
        __hip_bfloat16* t = cur; cur = nxt; nxt = t;
    }

    fc_kernel<<<NB, 256, 0, stream>>>(jk, fc_w, fc_b, (float*)d_out, n);
}

// Round 11
// 352.506 us; speedup vs baseline: 1.1319x; 1.0861x over previous
//
#include <hip/hip_runtime.h>
#include <hip/hip_bf16.h>

#define H 16
#define F_IN 58
#define NPB 16     // nodes per block in t0 (256 threads / 16 lanes)
#define SCH 4160   // max edges per stage chunk (LDS sort capacity)
#define ECAP 4096  // LDS edge-cache capacity in agg (64 nodes * avg 32 = 2048 typ)

static inline size_t align256(size_t x) { return (x + 255) & ~(size_t)255; }

__device__ inline float bfu2f(unsigned short u) {
    return __uint_as_float(((unsigned)u) << 16);
}

// ---------- dtype detection: int64 vs int32 edge_index ----------
__global__ void detect_kernel(const int* eidx32, int* flag) {
    __shared__ int any;
    if (threadIdx.x == 0) any = 0;
    __syncthreads();
    int nz = 0;
    for (int j = threadIdx.x; j < 1024; j += 256)
        nz |= (eidx32[2 * j + 1] != 0);
    if (nz) atomicOr(&any, 1);
    __syncthreads();
    if (threadIdx.x == 0) *flag = (any == 0) ? 1 : 0;  // all-zero odd words -> int64
}

__device__ inline int load_idx(const void* eidx, long i, int is64) {
    if (is64) return (int)((const long long*)eidx)[i];
    return ((const int*)eidx)[i];
}

// ---------- bucket counts (391 bins of 256 nodes), vectorized dst reads ----------
__global__ void bcount_kernel(const void* eidx, int E, const int* flag64,
                              int n, int* bucketcnt) {
    __shared__ int hist[512];
    int is64 = *flag64;
    int B = (n + 255) >> 8;
    int tid = threadIdx.x;
    for (int j = tid; j < B; j += 256) hist[j] = 0;
    __syncthreads();
    int stride = gridDim.x * blockDim.x;
    int gid = blockIdx.x * blockDim.x + tid;
    if (is64) {
        const longlong2* d2 = (const longlong2*)((const long long*)eidx + E);
        int half = E >> 1;
        for (int i = gid; i < half; i += stride) {
            longlong2 q = d2[i];
            atomicAdd(&hist[((int)q.x) >> 8], 1);
            atomicAdd(&hist[((int)q.y) >> 8], 1);
        }
        if (gid == 0 && (E & 1)) {
            int d = (int)((const long long*)eidx)[2 * (long)E - 1];
            atomicAdd(&hist[d >> 8], 1);
        }
    } else {
        const int4* d4 = (const int4*)((const int*)eidx + E);
        int quarter = E >> 2;
        for (int i = gid; i < quarter; i += stride) {
            int4 q = d4[i];
            atomicAdd(&hist[q.x >> 8], 1);
            atomicAdd(&hist[q.y >> 8], 1);
            atomicAdd(&hist[q.z >> 8], 1);
            atomicAdd(&hist[q.w >> 8], 1);
        }
        for (int i = (quarter << 2) + gid; i < E; i += stride) {
            int d = ((const int*)eidx)[(long)E + i];
            atomicAdd(&hist[d >> 8], 1);
        }
    }
    __syncthreads();
    for (int j = tid; j < B; j += 256)
        if (hist[j]) atomicAdd(&bucketcnt[j], hist[j]);
}

// ---------- exclusive scan of bucket counts (single block, B <= 512) ----------
__global__ void bscan_kernel(const int* bucketcnt, int B, int E,
                             int* gcur, int* bucketbase) {
    __shared__ int tmp[512];
    int tid = threadIdx.x;
    int val = (tid < B) ? bucketcnt[tid] : 0;
    tmp[tid] = val;
    __syncthreads();
    for (int off = 1; off < 512; off <<= 1) {
        int t = (tid >= off) ? tmp[tid - off] : 0;
        __syncthreads();
        tmp[tid] += t;
        __syncthreads();
    }
    if (tid < B) {
        int ex = tmp[tid] - val;
        gcur[tid] = ex;
        bucketbase[tid] = ex;
    }
    if (tid == 0) bucketbase[B] = E;
}

// ---------- stage: LDS counting-sort each chunk by bucket, write coalesced runs ----------
__global__ void stage_kernel(const void* eidx, int E, const int* flag64,
                             int n, int* gcur, unsigned* staging) {
    __shared__ unsigned sorted[SCH];
    __shared__ unsigned short sbuck[SCH];
    __shared__ int hist[512];
    __shared__ int hbase[512];
    __shared__ int lofs[512];
    __shared__ int cursor[512];
    __shared__ int ps[256];

    int is64 = *flag64;
    int tid = threadIdx.x;
    int chunk = (E + gridDim.x - 1) / gridDim.x;
    int s0 = blockIdx.x * chunk;
    int s1 = min(E, s0 + chunk);
    int c = s1 - s0;
    if (c <= 0) return;

    for (int j = tid; j < 512; j += 256) { hist[j] = 0; cursor[j] = 0; }
    __syncthreads();

    // pass A: per-chunk bucket histogram (vectorized dst reads)
    if (is64) {
        const longlong2* dp = (const longlong2*)((const long long*)eidx + E + s0);
        int m = c >> 1;
        for (int i = tid; i < m; i += 256) {
            longlong2 q = dp[i];
            atomicAdd(&hist[((int)q.x) >> 8], 1);
            atomicAdd(&hist[((int)q.y) >> 8], 1);
        }
        if (tid == 0 && (c & 1)) {
            int d = (int)((const long long*)eidx)[(long)E + s1 - 1];
            atomicAdd(&hist[d >> 8], 1);
        }
    } else {
        const int2* dp = (const int2*)((const int*)eidx + E + s0);
        int m = c >> 1;
        for (int i = tid; i < m; i += 256) {
            int2 q = dp[i];
            atomicAdd(&hist[q.x >> 8], 1);
            atomicAdd(&hist[q.y >> 8], 1);
        }
        if (tid == 0 && (c & 1)) {
            int d = ((const int*)eidx)[(long)E + s1 - 1];
            atomicAdd(&hist[d >> 8], 1);
        }
    }
    __syncthreads();

    // pass B: reserve global run per bucket
    for (int j = tid; j < 512; j += 256) {
        int cc = hist[j];
        hbase[j] = cc ? atomicAdd(&gcur[j], cc) : 0;
    }

    // pass C: exclusive scan of hist -> lofs (512 bins, 256 threads)
    int a0 = hist[2 * tid], a1 = hist[2 * tid + 1];
    ps[tid] = a0 + a1;
    __syncthreads();
    for (int off = 1; off < 256; off <<= 1) {
        int t = (tid >= off) ? ps[tid - off] : 0;
        __syncthreads();
        ps[tid] += t;
        __syncthreads();
    }
    int ex = ps[tid] - (a0 + a1);
    lofs[2 * tid] = ex;
    lofs[2 * tid + 1] = ex + a0;
    __syncthreads();

    // pass D: scatter into LDS in bucket-sorted order (vectorized src+dst reads)
    if (is64) {
        const longlong2* sp = (const longlong2*)((const long long*)eidx + s0);
        const longlong2* dp = (const longlong2*)((const long long*)eidx + E + s0);
        int m = c >> 1;
        for (int i = tid; i < m; i += 256) {
            longlong2 qs = sp[i];
            longlong2 qd = dp[i];
            int s = (int)qs.x, d = (int)qd.x;
            int b = d >> 8;
            int loc = lofs[b] + atomicAdd(&cursor[b], 1);
            sorted[loc] = (unsigned)s | ((unsigned)(d & 255) << 17);
            sbuck[loc] = (unsigned short)b;
            s = (int)qs.y; d = (int)qd.y;
            b = d >> 8;
            loc = lofs[b] + atomicAdd(&cursor[b], 1);
            sorted[loc] = (unsigned)s | ((unsigned)(d & 255) << 17);
            sbuck[loc] = (unsigned short)b;
        }
        if (tid == 0 && (c & 1)) {
            int s = (int)((const long long*)eidx)[(long)s1 - 1];
            int d = (int)((const long long*)eidx)[(long)E + s1 - 1];
            int b = d >> 8;
            int loc = lofs[b] + atomicAdd(&cursor[b], 1);
            sorted[loc] = (unsigned)s | ((unsigned)(d & 255) << 17);
            sbuck[loc] = (unsigned short)b;
        }
    } else {
        const int2* sp = (const int2*)((const int*)eidx + s0);
        const int2* dp = (const int2*)((const int*)eidx + E + s0);
        int m = c >> 1;
        for (int i = tid; i < m; i += 256) {
            int2 qs = sp[i];
            int2 qd = dp[i];
            int b = qd.x >> 8;
            int loc = lofs[b] + atomicAdd(&cursor[b], 1);
            sorted[loc] = (unsigned)qs.x | ((unsigned)(qd.x & 255) << 17);
            sbuck[loc] = (unsigned short)b;
            b = qd.y >> 8;
            loc = lofs[b] + atomicAdd(&cursor[b], 1);
            sorted[loc] = (unsigned)qs.y | ((unsigned)(qd.y & 255) << 17);
            sbuck[loc] = (unsigned short)b;
        }
        if (tid == 0 && (c & 1)) {
            int s = ((const int*)eidx)[(long)s1 - 1];
            int d = ((const int*)eidx)[(long)E + s1 - 1];
            int b = d >> 8;
            int loc = lofs[b] + atomicAdd(&cursor[b], 1);
            sorted[loc] = (unsigned)s | ((unsigned)(d & 255) << 17);
            sbuck[loc] = (unsigned short)b;
        }
    }
    __syncthreads();

    // pass E: linear LDS read, coalesced run writes to global
    for (int i = tid; i < c; i += 256) {
        int b = sbuck[i];
        staging[hbase[b] + (i - lofs[b])] = sorted[i];
    }
}

// ---------- per-bucket local hist + scan -> rowstart/dinv, node-sorted ed ----------
__global__ void fine_kernel(const unsigned* __restrict__ staging,
                            const int* __restrict__ bucketbase, int n, int E,
                            int* __restrict__ ed, int* __restrict__ rowstart,
                            float* __restrict__ dinv) {
    __shared__ int lcnt[256];
    __shared__ int lofs[256];
    __shared__ int lcur[256];
    int tid = threadIdx.x;
    int b = blockIdx.x;
    int node0 = b << 8;
    int start = bucketbase[b], end = bucketbase[b + 1];
    int cnt = end - start;
    lcnt[tid] = 0;
    lcur[tid] = 0;
    __syncthreads();
    for (int i = tid; i < cnt; i += 256) {
        unsigned w = staging[start + i];
        atomicAdd(&lcnt[w >> 17], 1);
    }
    __syncthreads();
    int val = lcnt[tid];
    lofs[tid] = val;
    __syncthreads();
    for (int off = 1; off < 256; off <<= 1) {
        int t = (tid >= off) ? lofs[tid - off] : 0;
        __syncthreads();
        lofs[tid] += t;
        __syncthreads();
    }
    int ex = lofs[tid] - val;
    __syncthreads();
    lofs[tid] = ex;
    __syncthreads();
    int node = node0 + tid;
    if (node < n) {
        rowstart[node] = start + ex;
        dinv[node] = rsqrtf((float)(val + 1));
    }
    if (node == 0) rowstart[n] = E;
    for (int i = tid; i < cnt; i += 256) {
        unsigned w = staging[start + i];
        int ld = (int)(w >> 17);
        int pos = start + lofs[ld] + atomicAdd(&lcur[ld], 1);
        ed[pos] = (int)(w & 0x1FFFFu);
    }
}

// ---------- layer 0 dense transform: hw0 = bf16(dinv * (x @ W0)) ----------
__global__ void t0_kernel(const float* __restrict__ x, const float* __restrict__ W0,
                          const float* __restrict__ dinv,
                          __hip_bfloat16* __restrict__ hw, int n) {
    __shared__ float Wl[F_IN * H];
    int tid = threadIdx.x;
    for (int j = tid; j < F_IN * H; j += 256) Wl[j] = W0[j];
    __syncthreads();
    int g = tid >> 4, f = tid & 15;
    int v = blockIdx.x * NPB + g;
    if (v >= n) return;
    const float* xr = x + (long)v * F_IN;
    float acc = 0.f;
#pragma unroll
    for (int k = 0; k < F_IN; ++k) acc += xr[k] * Wl[k * H + f];
    hw[v * H + f] = __float2bfloat16(acc * dinv[v]);
}

// ---------- aggregation: 64 nodes/block, 4 lanes/node x 4 features, LDS edge cache ----------
// hw holds dinv-scaled features (bf16); agg = dinv[v]*(sum_src hw[src] + hw[v])
// Last layer fuses the FC: out[v] = dot(jk_max, fc_w) + fc_b (no jk store).
__global__ __launch_bounds__(256) void agg_kernel(
    const int* __restrict__ ed, const int* __restrict__ rowstart,
    const float* __restrict__ dinv, const __hip_bfloat16* __restrict__ hw,
    const float* __restrict__ bias, const float* __restrict__ Wnext,
    float* __restrict__ jk, __hip_bfloat16* __restrict__ hw_next,
    const float* __restrict__ fcw, const float* __restrict__ fcb,
    float* __restrict__ out,
    int n, int first, int has_next, int last) {
    __shared__ float Wl[H * H];
    __shared__ int eds[ECAP];
    __shared__ int rs[65];
    int tid = threadIdx.x;
    if (has_next) Wl[tid] = Wnext[tid];  // 256 threads == 16x16
    int node0 = blockIdx.x * 64;
    int nn = min(64, n - node0);         // nodes in this block (>=1)
    if (tid <= nn) rs[tid] = rowstart[node0 + tid];
    __syncthreads();
    int s0 = rs[0];
    int cnt = rs[nn] - s0;
    for (int i = tid; i < cnt && i < ECAP; i += 256) eds[i] = ed[s0 + i];
    __syncthreads();

    int g = tid >> 2, l = tid & 3;       // 64 nodes/block, 4 lanes/node
    if (g >= nn) return;
    int v = node0 + g;
    int fb = l * 4;                      // feature quad base
    const unsigned short* hwu = (const unsigned short*)hw;

    float4 accA = make_float4(0.f, 0.f, 0.f, 0.f);
    float4 accB = make_float4(0.f, 0.f, 0.f, 0.f);
    int ls = rs[g] - s0, le = rs[g + 1] - s0;

    if (le <= ECAP) {                    // fast path: indices from LDS
        int i = ls;
        for (; i + 8 <= le; i += 8) {
            int t0 = eds[i],     t1 = eds[i + 1], t2 = eds[i + 2], t3 = eds[i + 3];
            int t4 = eds[i + 4], t5 = eds[i + 5], t6 = eds[i + 6], t7 = eds[i + 7];
            ushort4 u0 = *(const ushort4*)(hwu + t0 * H + fb);
            ushort4 u1 = *(const ushort4*)(hwu + t1 * H + fb);
            ushort4 u2 = *(const ushort4*)(hwu + t2 * H + fb);
            ushort4 u3 = *(const ushort4*)(hwu + t3 * H + fb);
            ushort4 u4 = *(const ushort4*)(hwu + t4 * H + fb);
            ushort4 u5 = *(const ushort4*)(hwu + t5 * H + fb);
            ushort4 u6 = *(const ushort4*)(hwu + t6 * H + fb);
            ushort4 u7 = *(const ushort4*)(hwu + t7 * H + fb);
            accA.x += bfu2f(u0.x); accA.y += bfu2f(u0.y); accA.z += bfu2f(u0.z); accA.w += bfu2f(u0.w);
            accB.x += bfu2f(u1.x); accB.y += bfu2f(u1.y); accB.z += bfu2f(u1.z); accB.w += bfu2f(u1.w);
            accA.x += bfu2f(u2.x); accA.y += bfu2f(u2.y); accA.z += bfu2f(u2.z); accA.w += bfu2f(u2.w);
            accB.x += bfu2f(u3.x); accB.y += bfu2f(u3.y); accB.z += bfu2f(u3.z); accB.w += bfu2f(u3.w);
            accA.x += bfu2f(u4.x); accA.y += bfu2f(u4.y); accA.z += bfu2f(u4.z); accA.w += bfu2f(u4.w);
            accB.x += bfu2f(u5.x); accB.y += bfu2f(u5.y); accB.z += bfu2f(u5.z); accB.w += bfu2f(u5.w);
            accA.x += bfu2f(u6.x); accA.y += bfu2f(u6.y); accA.z += bfu2f(u6.z); accA.w += bfu2f(u6.w);
            accB.x += bfu2f(u7.x); accB.y += bfu2f(u7.y); accB.z += bfu2f(u7.z); accB.w += bfu2f(u7.w);
        }
        for (; i < le; ++i) {
            ushort4 u = *(const ushort4*)(hwu + eds[i] * H + fb);
            accA.x += bfu2f(u.x); accA.y += bfu2f(u.y); accA.z += bfu2f(u.z); accA.w += bfu2f(u.w);
        }
    } else {                             // fallback: indices from global (huge block)
        int i = s0 + ls, e = s0 + le;
        for (; i + 8 <= e; i += 8) {
            int t0 = ed[i],     t1 = ed[i + 1], t2 = ed[i + 2], t3 = ed[i + 3];
            int t4 = ed[i + 4], t5 = ed[i + 5], t6 = ed[i + 6], t7 = ed[i + 7];
            ushort4 u0 = *(const ushort4*)(hwu + t0 * H + fb);
            ushort4 u1 = *(const ushort4*)(hwu + t1 * H + fb);
            ushort4 u2 = *(const ushort4*)(hwu + t2 * H + fb);
            ushort4 u3 = *(const ushort4*)(hwu + t3 * H + fb);
            ushort4 u4 = *(const ushort4*)(hwu + t4 * H + fb);
            ushort4 u5 = *(const ushort4*)(hwu + t5 * H + fb);
            ushort4 u6 = *(const ushort4*)(hwu + t6 * H + fb);
            ushort4 u7 = *(const ushort4*)(hwu + t7 * H + fb);
            accA.x += bfu2f(u0.x); accA.y += bfu2f(u0.y); accA.z += bfu2f(u0.z); accA.w += bfu2f(u0.w);
            accB.x += bfu2f(u1.x); accB.y += bfu2f(u1.y); accB.z += bfu2f(u1.z); accB.w += bfu2f(u1.w);
            accA.x += bfu2f(u2.x); accA.y += bfu2f(u2.y); accA.z += bfu2f(u2.z); accA.w += bfu2f(u2.w);
            accB.x += bfu2f(u3.x); accB.y += bfu2f(u3.y); accB.z += bfu2f(u3.z); accB.w += bfu2f(u3.w);
            accA.x += bfu2f(u4.x); accA.y += bfu2f(u4.y); accA.z += bfu2f(u4.z); accA.w += bfu2f(u4.w);
            accB.x += bfu2f(u5.x); accB.y += bfu2f(u5.y); accB.z += bfu2f(u5.z); accB.w += bfu2f(u5.w);
            accA.x += bfu2f(u6.x); accA.y += bfu2f(u6.y); accA.z += bfu2f(u6.z); accA.w += bfu2f(u6.w);
            accB.x += bfu2f(u7.x); accB.y += bfu2f(u7.y); accB.z += bfu2f(u7.z); accB.w += bfu2f(u7.w);
        }
        for (; i < e; ++i) {
            ushort4 u = *(const ushort4*)(hwu + ed[i] * H + fb);
            accA.x += bfu2f(u.x); accA.y += bfu2f(u.y); accA.z += bfu2f(u.z); accA.w += bfu2f(u.w);
        }
    }

    // self-loop + bias + relu
    ushort4 us = *(const ushort4*)(hwu + (size_t)v * H + fb);
    float dv = dinv[v];
    float4 bv = *(const float4*)(bias + fb);
    float4 val;
    val.x = fmaxf((accA.x + accB.x + bfu2f(us.x)) * dv + bv.x, 0.f);
    val.y = fmaxf((accA.y + accB.y + bfu2f(us.y)) * dv + bv.y, 0.f);
    val.z = fmaxf((accA.z + accB.z + bfu2f(us.z)) * dv + bv.z, 0.f);
    val.w = fmaxf((accA.w + accB.w + bfu2f(us.w)) * dv + bv.w, 0.f);

    // jk running max
    float4* jkp = (float4*)(jk + (size_t)v * H + fb);
    float4 jv = val;
    if (!first) {
        float4 jo = *jkp;
        jv.x = fmaxf(jo.x, val.x); jv.y = fmaxf(jo.y, val.y);
        jv.z = fmaxf(jo.z, val.z); jv.w = fmaxf(jo.w, val.w);
    }
    if (!last) {
        *jkp = jv;
    } else {
        // fused FC: out[v] = dot(jv_all16, fc_w) + fc_b
        float4 wv = *(const float4*)(fcw + fb);
        float partial = jv.x * wv.x + jv.y * wv.y + jv.z * wv.z + jv.w * wv.w;
        partial += __shfl_xor(partial, 1, 4);
        partial += __shfl_xor(partial, 2, 4);
        if (l == 0) out[v] = partial + fcb[0];
    }

    // fused next-layer transform: out[f'] = sum_k val_all[k] * W[k][f']
    if (has_next) {
        float4 o = make_float4(0.f, 0.f, 0.f, 0.f);
#pragma unroll
        for (int kq = 0; kq < 4; ++kq) {
            float4 vk;
            vk.x = __shfl(val.x, kq, 4);
            vk.y = __shfl(val.y, kq, 4);
            vk.z = __shfl(val.z, kq, 4);
            vk.w = __shfl(val.w, kq, 4);
            float4 w0 = *(const float4*)(Wl + (4 * kq + 0) * H + fb);
            float4 w1 = *(const float4*)(Wl + (4 * kq + 1) * H + fb);
            float4 w2 = *(const float4*)(Wl + (4 * kq + 2) * H + fb);
            float4 w3 = *(const float4*)(Wl + (4 * kq + 3) * H + fb);
            o.x += vk.x * w0.x + vk.y * w1.x + vk.z * w2.x + vk.w * w3.x;
            o.y += vk.x * w0.y + vk.y * w1.y + vk.z * w2.y + vk.w * w3.y;
            o.z += vk.x * w0.z + vk.y * w1.z + vk.z * w2.z + vk.w * w3.z;
            o.w += vk.x * w0.w + vk.y * w1.w + vk.z * w2.w + vk.w * w3.w;
        }
        ushort4 ob;
        ob.x = (unsigned short)(__bfloat16_as_ushort(__float2bfloat16(o.x * dv)));
        ob.y = (unsigned short)(__bfloat16_as_ushort(__float2bfloat16(o.y * dv)));
        ob.z = (unsigned short)(__bfloat16_as_ushort(__float2bfloat16(o.z * dv)));
        ob.w = (unsigned short)(__bfloat16_as_ushort(__float2bfloat16(o.w * dv)));
        *(ushort4*)((unsigned short*)hw_next + (size_t)v * H + fb) = ob;
    }
}

extern "C" void kernel_launch(void* const* d_in, const int* in_sizes, int n_in,
                              void* d_out, int out_size, void* d_ws, size_t ws_size,
                              hipStream_t stream) {
    const float* x    = (const float*)d_in[0];
    const void*  eidx = d_in[1];
    const float* W0   = (const float*)d_in[2];
    const float* Ws   = (const float*)d_in[3];
    const float* bs   = (const float*)d_in[4];
    const float* fc_w = (const float*)d_in[5];
    const float* fc_b = (const float*)d_in[6];

    int n = in_sizes[0] / F_IN;        // 100000
    int E = in_sizes[1] / 2;           // 3200000
    int L = in_sizes[4] / H;           // 10

    // workspace carve-up
    char* w = (char*)d_ws;
    size_t off = 0;
    int* rowstart    = (int*)(w + off); off += align256((size_t)(n + 1) * 4);
    float* dinv      = (float*)(w + off); off += align256((size_t)n * 4);
    int* bucketcnt   = (int*)(w + off); off += align256(512 * 4);
    int* bucketbase  = (int*)(w + off); off += align256(513 * 4);
    int* gcur        = (int*)(w + off); off += align256(512 * 4);
    int* flag64      = (int*)(w + off); off += align256(256);
    unsigned* stg    = (unsigned*)(w + off); off += align256((size_t)E * 4);
    int* ed          = (int*)(w + off); off += align256((size_t)E * 4);
    __hip_bfloat16* hwA = (__hip_bfloat16*)(w + off); off += align256((size_t)n * H * 2);
    __hip_bfloat16* hwB = (__hip_bfloat16*)(w + off); off += align256((size_t)n * H * 2);
    float* jk        = (float*)(w + off); off += align256((size_t)n * H * 4);

    int NB = (n + 255) / 256;          // 391 buckets of 256 nodes

    hipMemsetAsync(bucketcnt, 0, 512 * 4, stream);
    detect_kernel<<<1, 256, 0, stream>>>((const int*)eidx, flag64);
    bcount_kernel<<<512, 256, 0, stream>>>(eidx, E, flag64, n, bucketcnt);
    bscan_kernel<<<1, 512, 0, stream>>>(bucketcnt, NB, E, gcur, bucketbase);
    int SG = (E + 4095) / 4096;        // chunk <= 4096 <= SCH
    stage_kernel<<<SG, 256, 0, stream>>>(eidx, E, flag64, n, gcur, stg);
    fine_kernel<<<NB, 256, 0, stream>>>(stg, bucketbase, n, E, ed, rowstart, dinv);

    int ngrid = (n + NPB - 1) / NPB;   // 6250
    t0_kernel<<<ngrid, 256, 0, stream>>>(x, W0, dinv, hwA, n);

    __hip_bfloat16* cur = hwA;
    __hip_bfloat16* nxt = hwB;
    int agrid = (n + 63) / 64;         // 1563
    for (int l = 0; l < L; ++l) {
        const float* bias  = bs + (size_t)l * H;
        const float* Wnext = (l < L - 1) ? (Ws + (size_t)l * H * H) : nullptr;
        agg_kernel<<<agrid, 256, 0, stream>>>(ed, rowstart, dinv, cur, bias, Wnext,
                                              jk, nxt, fc_w, fc_b, (float*)d_out,
                                              n, (l == 0) ? 1 : 0,
                                              (l < L - 1) ? 1 : 0,
                                              (l == L - 1) ? 1 : 0);
        __hip_bfloat16* t = cur; cur = nxt; nxt = t;
    }
}

// Round 12
// 336.650 us; speedup vs baseline: 1.1852x; 1.0471x over previous
//
#include <hip/hip_runtime.h>
#include <hip/hip_bf16.h>

#define H 16
#define F_IN 58
#define NPB 16     // nodes per block in t0 (256 threads / 16 lanes)
#define SCH 4160   // max edges per stage chunk (LDS sort capacity)
#define ECAP 4096  // LDS edge-cache capacity in agg (64 nodes * avg 32 = 2048 typ)

static inline size_t align256(size_t x) { return (x + 255) & ~(size_t)255; }

__device__ inline float bfu2f(unsigned short u) {
    return __uint_as_float(((unsigned)u) << 16);
}

// ---------- dtype detection: int64 vs int32 edge_index ----------
__global__ void detect_kernel(const int* eidx32, int* flag) {
    __shared__ int any;
    if (threadIdx.x == 0) any = 0;
    __syncthreads();
    int nz = 0;
    for (int j = threadIdx.x; j < 1024; j += 256)
        nz |= (eidx32[2 * j + 1] != 0);
    if (nz) atomicOr(&any, 1);
    __syncthreads();
    if (threadIdx.x == 0) *flag = (any == 0) ? 1 : 0;  // all-zero odd words -> int64
}

__device__ inline int load_idx(const void* eidx, long i, int is64) {
    if (is64) return (int)((const long long*)eidx)[i];
    return ((const int*)eidx)[i];
}

// ---------- bucket counts (391 bins of 256 nodes), vectorized dst reads ----------
__global__ void bcount_kernel(const void* eidx, int E, const int* flag64,
                              int n, int* bucketcnt) {
    __shared__ int hist[512];
    int is64 = *flag64;
    int B = (n + 255) >> 8;
    int tid = threadIdx.x;
    for (int j = tid; j < B; j += 256) hist[j] = 0;
    __syncthreads();
    int stride = gridDim.x * blockDim.x;
    int gid = blockIdx.x * blockDim.x + tid;
    if (is64) {
        const longlong2* d2 = (const longlong2*)((const long long*)eidx + E);
        int half = E >> 1;
        for (int i = gid; i < half; i += stride) {
            longlong2 q = d2[i];
            atomicAdd(&hist[((int)q.x) >> 8], 1);
            atomicAdd(&hist[((int)q.y) >> 8], 1);
        }
        if (gid == 0 && (E & 1)) {
            int d = (int)((const long long*)eidx)[2 * (long)E - 1];
            atomicAdd(&hist[d >> 8], 1);
        }
    } else {
        const int4* d4 = (const int4*)((const int*)eidx + E);
        int quarter = E >> 2;
        for (int i = gid; i < quarter; i += stride) {
            int4 q = d4[i];
            atomicAdd(&hist[q.x >> 8], 1);
            atomicAdd(&hist[q.y >> 8], 1);
            atomicAdd(&hist[q.z >> 8], 1);
            atomicAdd(&hist[q.w >> 8], 1);
        }
        for (int i = (quarter << 2) + gid; i < E; i += stride) {
            int d = ((const int*)eidx)[(long)E + i];
            atomicAdd(&hist[d >> 8], 1);
        }
    }
    __syncthreads();
    for (int j = tid; j < B; j += 256)
        if (hist[j]) atomicAdd(&bucketcnt[j], hist[j]);
}

// ---------- exclusive scan of bucket counts (single block, B <= 512) ----------
__global__ void bscan_kernel(const int* bucketcnt, int B, int E,
                             int* gcur, int* bucketbase) {
    __shared__ int tmp[512];
    int tid = threadIdx.x;
    int val = (tid < B) ? bucketcnt[tid] : 0;
    tmp[tid] = val;
    __syncthreads();
    for (int off = 1; off < 512; off <<= 1) {
        int t = (tid >= off) ? tmp[tid - off] : 0;
        __syncthreads();
        tmp[tid] += t;
        __syncthreads();
    }
    if (tid < B) {
        int ex = tmp[tid] - val;
        gcur[tid] = ex;
        bucketbase[tid] = ex;
    }
    if (tid == 0) bucketbase[B] = E;
}

// ---------- stage: LDS counting-sort each chunk by bucket, write coalesced runs ----------
__global__ void stage_kernel(const void* eidx, int E, const int* flag64,
                             int n, int* gcur, unsigned* staging) {
    __shared__ unsigned sorted[SCH];
    __shared__ unsigned short sbuck[SCH];
    __shared__ int hist[512];
    __shared__ int hbase[512];
    __shared__ int lofs[512];
    __shared__ int cursor[512];
    __shared__ int ps[256];

    int is64 = *flag64;
    int tid = threadIdx.x;
    int chunk = (E + gridDim.x - 1) / gridDim.x;
    int s0 = blockIdx.x * chunk;
    int s1 = min(E, s0 + chunk);
    int c = s1 - s0;
    if (c <= 0) return;

    for (int j = tid; j < 512; j += 256) { hist[j] = 0; cursor[j] = 0; }
    __syncthreads();

    // pass A: per-chunk bucket histogram (vectorized dst reads)
    if (is64) {
        const longlong2* dp = (const longlong2*)((const long long*)eidx + E + s0);
        int m = c >> 1;
        for (int i = tid; i < m; i += 256) {
            longlong2 q = dp[i];
            atomicAdd(&hist[((int)q.x) >> 8], 1);
            atomicAdd(&hist[((int)q.y) >> 8], 1);
        }
        if (tid == 0 && (c & 1)) {
            int d = (int)((const long long*)eidx)[(long)E + s1 - 1];
            atomicAdd(&hist[d >> 8], 1);
        }
    } else {
        const int2* dp = (const int2*)((const int*)eidx + E + s0);
        int m = c >> 1;
        for (int i = tid; i < m; i += 256) {
            int2 q = dp[i];
            atomicAdd(&hist[q.x >> 8], 1);
            atomicAdd(&hist[q.y >> 8], 1);
        }
        if (tid == 0 && (c & 1)) {
            int d = ((const int*)eidx)[(long)E + s1 - 1];
            atomicAdd(&hist[d >> 8], 1);
        }
    }
    __syncthreads();

    // pass B: reserve global run per bucket
    for (int j = tid; j < 512; j += 256) {
        int cc = hist[j];
        hbase[j] = cc ? atomicAdd(&gcur[j], cc) : 0;
    }

    // pass C: exclusive scan of hist -> lofs (512 bins, 256 threads)
    int a0 = hist[2 * tid], a1 = hist[2 * tid + 1];
    ps[tid] = a0 + a1;
    __syncthreads();
    for (int off = 1; off < 256; off <<= 1) {
        int t = (tid >= off) ? ps[tid - off] : 0;
        __syncthreads();
        ps[tid] += t;
        __syncthreads();
    }
    int ex = ps[tid] - (a0 + a1);
    lofs[2 * tid] = ex;
    lofs[2 * tid + 1] = ex + a0;
    __syncthreads();

    // pass D: scatter into LDS in bucket-sorted order (vectorized src+dst reads)
    if (is64) {
        const longlong2* sp = (const longlong2*)((const long long*)eidx + s0);
        const longlong2* dp = (const longlong2*)((const long long*)eidx + E + s0);
        int m = c >> 1;
        for (int i = tid; i < m; i += 256) {
            longlong2 qs = sp[i];
            longlong2 qd = dp[i];
            int s = (int)qs.x, d = (int)qd.x;
            int b = d >> 8;
            int loc = lofs[b] + atomicAdd(&cursor[b], 1);
            sorted[loc] = (unsigned)s | ((unsigned)(d & 255) << 17);
            sbuck[loc] = (unsigned short)b;
            s = (int)qs.y; d = (int)qd.y;
            b = d >> 8;
            loc = lofs[b] + atomicAdd(&cursor[b], 1);
            sorted[loc] = (unsigned)s | ((unsigned)(d & 255) << 17);
            sbuck[loc] = (unsigned short)b;
        }
        if (tid == 0 && (c & 1)) {
            int s = (int)((const long long*)eidx)[(long)s1 - 1];
            int d = (int)((const long long*)eidx)[(long)E + s1 - 1];
            int b = d >> 8;
            int loc = lofs[b] + atomicAdd(&cursor[b], 1);
            sorted[loc] = (unsigned)s | ((unsigned)(d & 255) << 17);
            sbuck[loc] = (unsigned short)b;
        }
    } else {
        const int2* sp = (const int2*)((const int*)eidx + s0);
        const int2* dp = (const int2*)((const int*)eidx + E + s0);
        int m = c >> 1;
        for (int i = tid; i < m; i += 256) {
            int2 qs = sp[i];
            int2 qd = dp[i];
            int b = qd.x >> 8;
            int loc = lofs[b] + atomicAdd(&cursor[b], 1);
            sorted[loc] = (unsigned)qs.x | ((unsigned)(qd.x & 255) << 17);
            sbuck[loc] = (unsigned short)b;
            b = qd.y >> 8;
            loc = lofs[b] + atomicAdd(&cursor[b], 1);
            sorted[loc] = (unsigned)qs.y | ((unsigned)(qd.y & 255) << 17);
            sbuck[loc] = (unsigned short)b;
        }
        if (tid == 0 && (c & 1)) {
            int s = ((const int*)eidx)[(long)s1 - 1];
            int d = ((const int*)eidx)[(long)E + s1 - 1];
            int b = d >> 8;
            int loc = lofs[b] + atomicAdd(&cursor[b], 1);
            sorted[loc] = (unsigned)s | ((unsigned)(d & 255) << 17);
            sbuck[loc] = (unsigned short)b;
        }
    }
    __syncthreads();

    // pass E: linear LDS read, coalesced run writes to global
    for (int i = tid; i < c; i += 256) {
        int b = sbuck[i];
        staging[hbase[b] + (i - lofs[b])] = sorted[i];
    }
}

// ---------- per-bucket local hist + scan -> rowstart/dinv, node-sorted ed ----------
// stg reads vectorized (order-independent passes; scalar head/tail, no cross-bucket reads)
__global__ void fine_kernel(const unsigned* __restrict__ staging,
                            const int* __restrict__ bucketbase, int n, int E,
                            int* __restrict__ ed, int* __restrict__ rowstart,
                            float* __restrict__ dinv) {
    __shared__ int lcnt[256];
    __shared__ int lofs[256];
    __shared__ int lcur[256];
    int tid = threadIdx.x;
    int b = blockIdx.x;
    int node0 = b << 8;
    int start = bucketbase[b], end = bucketbase[b + 1];
    int cnt = end - start;
    lcnt[tid] = 0;
    lcur[tid] = 0;
    __syncthreads();

    int head = min((4 - (start & 3)) & 3, cnt);
    int body = (cnt - head) & ~3;
    const uint4* sp = (const uint4*)(staging + start + head);

    // pass 1: per-node histogram
    for (int i = tid; i < head; i += 256)
        atomicAdd(&lcnt[staging[start + i] >> 17], 1);
    for (int i = tid; i < (body >> 2); i += 256) {
        uint4 q = sp[i];
        atomicAdd(&lcnt[q.x >> 17], 1);
        atomicAdd(&lcnt[q.y >> 17], 1);
        atomicAdd(&lcnt[q.z >> 17], 1);
        atomicAdd(&lcnt[q.w >> 17], 1);
    }
    for (int i = head + body + tid; i < cnt; i += 256)
        atomicAdd(&lcnt[staging[start + i] >> 17], 1);
    __syncthreads();

    int val = lcnt[tid];
    lofs[tid] = val;
    __syncthreads();
    for (int off = 1; off < 256; off <<= 1) {
        int t = (tid >= off) ? lofs[tid - off] : 0;
        __syncthreads();
        lofs[tid] += t;
        __syncthreads();
    }
    int ex = lofs[tid] - val;
    __syncthreads();
    lofs[tid] = ex;
    __syncthreads();
    int node = node0 + tid;
    if (node < n) {
        rowstart[node] = start + ex;
        dinv[node] = rsqrtf((float)(val + 1));
    }
    if (node == 0) rowstart[n] = E;

    // pass 2: node-sorted scatter (order-independent)
    for (int i = tid; i < head; i += 256) {
        unsigned w = staging[start + i];
        int ld = (int)(w >> 17);
        int pos = start + lofs[ld] + atomicAdd(&lcur[ld], 1);
        ed[pos] = (int)(w & 0x1FFFFu);
    }
    for (int i = tid; i < (body >> 2); i += 256) {
        uint4 q = sp[i];
        int ld = (int)(q.x >> 17);
        int pos = start + lofs[ld] + atomicAdd(&lcur[ld], 1);
        ed[pos] = (int)(q.x & 0x1FFFFu);
        ld = (int)(q.y >> 17);
        pos = start + lofs[ld] + atomicAdd(&lcur[ld], 1);
        ed[pos] = (int)(q.y & 0x1FFFFu);
        ld = (int)(q.z >> 17);
        pos = start + lofs[ld] + atomicAdd(&lcur[ld], 1);
        ed[pos] = (int)(q.z & 0x1FFFFu);
        ld = (int)(q.w >> 17);
        pos = start + lofs[ld] + atomicAdd(&lcur[ld], 1);
        ed[pos] = (int)(q.w & 0x1FFFFu);
    }
    for (int i = head + body + tid; i < cnt; i += 256) {
        unsigned w = staging[start + i];
        int ld = (int)(w >> 17);
        int pos = start + lofs[ld] + atomicAdd(&lcur[ld], 1);
        ed[pos] = (int)(w & 0x1FFFFu);
    }
}

// ---------- layer 0 dense transform: hw0 = bf16(dinv * (x @ W0)), x staged in LDS ----------
__global__ void t0_kernel(const float* __restrict__ x, const float* __restrict__ W0,
                          const float* __restrict__ dinv,
                          __hip_bfloat16* __restrict__ hw, int n) {
    __shared__ float Wl[F_IN * H];
    __shared__ float xs[NPB * F_IN];
    int tid = threadIdx.x;
    for (int j = tid; j < F_IN * H; j += 256) Wl[j] = W0[j];
    int v0 = blockIdx.x * NPB;
    int nrows = min(NPB, n - v0);
    int nfl = nrows * F_IN;
    const float* xb = x + (size_t)v0 * F_IN;   // 16*58*4 = 3712B: 16B aligned per block
    int nf4 = nfl >> 2;
    for (int j = tid; j < nf4; j += 256)
        ((float4*)xs)[j] = ((const float4*)xb)[j];
    for (int j = (nf4 << 2) + tid; j < nfl; j += 256)
        xs[j] = xb[j];
    __syncthreads();
    int g = tid >> 4, f = tid & 15;
    int v = v0 + g;
    if (v >= n) return;
    const float* xr = xs + g * F_IN;
    float acc = 0.f;
#pragma unroll
    for (int k = 0; k < F_IN; ++k) acc += xr[k] * Wl[k * H + f];
    hw[v * H + f] = __float2bfloat16(acc * dinv[v]);
}

// ---------- aggregation: 64 nodes/block, 4 lanes/node x 4 features, LDS edge cache ----------
// hw holds dinv-scaled features (bf16); agg = dinv[v]*(sum_src hw[src] + hw[v])
// Last layer fuses the FC: out[v] = dot(jk_max, fc_w) + fc_b (no jk store).
__global__ __launch_bounds__(256) void agg_kernel(
    const int* __restrict__ ed, const int* __restrict__ rowstart,
    const float* __restrict__ dinv, const __hip_bfloat16* __restrict__ hw,
    const float* __restrict__ bias, const float* __restrict__ Wnext,
    float* __restrict__ jk, __hip_bfloat16* __restrict__ hw_next,
    const float* __restrict__ fcw, const float* __restrict__ fcb,
    float* __restrict__ out,
    int n, int first, int has_next, int last) {
    __shared__ float Wl[H * H];
    __shared__ int eds[ECAP + 8];
    __shared__ int rs[65];
    int tid = threadIdx.x;
    if (has_next) Wl[tid] = Wnext[tid];  // 256 threads == 16x16
    int node0 = blockIdx.x * 64;
    int nn = min(64, n - node0);         // nodes in this block (>=1)
    if (tid <= nn) rs[tid] = rowstart[node0 + tid];
    __syncthreads();
    int s0 = rs[0];
    int aoff = s0 & 3;                   // eds[k] mirrors ed[s0 - aoff + k]
    int cnt = rs[nn] - s0;
    bool lds_ok = (cnt + aoff) <= ECAP;
    if (lds_ok) {
        int tot = cnt + aoff;
        int m4 = (tot + 3) >> 2;         // int4 count (over-read covered by slack)
        const int4* ep = (const int4*)(ed + (s0 - aoff));
        for (int i = tid; i < m4; i += 256)
            *(int4*)&eds[4 * i] = ep[i];
    }
    __syncthreads();

    int g = tid >> 2, l = tid & 3;       // 64 nodes/block, 4 lanes/node
    if (g >= nn) return;
    int v = node0 + g;
    int fb = l * 4;                      // feature quad base
    const unsigned short* hwu = (const unsigned short*)hw;

    float4 accA = make_float4(0.f, 0.f, 0.f, 0.f);
    float4 accB = make_float4(0.f, 0.f, 0.f, 0.f);

    if (lds_ok) {                        // fast path: indices from LDS
        int ls = rs[g] - s0 + aoff, le = rs[g + 1] - s0 + aoff;
        int i = ls;
        for (; i + 8 <= le; i += 8) {
            int t0 = eds[i],     t1 = eds[i + 1], t2 = eds[i + 2], t3 = eds[i + 3];
            int t4 = eds[i + 4], t5 = eds[i + 5], t6 = eds[i + 6], t7 = eds[i + 7];
            ushort4 u0 = *(const ushort4*)(hwu + t0 * H + fb);
            ushort4 u1 = *(const ushort4*)(hwu + t1 * H + fb);
            ushort4 u2 = *(const ushort4*)(hwu + t2 * H + fb);
            ushort4 u3 = *(const ushort4*)(hwu + t3 * H + fb);
            ushort4 u4 = *(const ushort4*)(hwu + t4 * H + fb);
            ushort4 u5 = *(const ushort4*)(hwu + t5 * H + fb);
            ushort4 u6 = *(const ushort4*)(hwu + t6 * H + fb);
            ushort4 u7 = *(const ushort4*)(hwu + t7 * H + fb);
            accA.x += bfu2f(u0.x); accA.y += bfu2f(u0.y); accA.z += bfu2f(u0.z); accA.w += bfu2f(u0.w);
            accB.x += bfu2f(u1.x); accB.y += bfu2f(u1.y); accB.z += bfu2f(u1.z); accB.w += bfu2f(u1.w);
            accA.x += bfu2f(u2.x); accA.y += bfu2f(u2.y); accA.z += bfu2f(u2.z); accA.w += bfu2f(u2.w);
            accB.x += bfu2f(u3.x); accB.y += bfu2f(u3.y); accB.z += bfu2f(u3.z); accB.w += bfu2f(u3.w);
            accA.x += bfu2f(u4.x); accA.y += bfu2f(u4.y); accA.z += bfu2f(u4.z); accA.w += bfu2f(u4.w);
            accB.x += bfu2f(u5.x); accB.y += bfu2f(u5.y); accB.z += bfu2f(u5.z); accB.w += bfu2f(u5.w);
            accA.x += bfu2f(u6.x); accA.y += bfu2f(u6.y); accA.z += bfu2f(u6.z); accA.w += bfu2f(u6.w);
            accB.x += bfu2f(u7.x); accB.y += bfu2f(u7.y); accB.z += bfu2f(u7.z); accB.w += bfu2f(u7.w);
        }
        for (; i < le; ++i) {
            ushort4 u = *(const ushort4*)(hwu + eds[i] * H + fb);
            accA.x += bfu2f(u.x); accA.y += bfu2f(u.y); accA.z += bfu2f(u.z); accA.w += bfu2f(u.w);
        }
    } else {                             // fallback: indices from global (huge block)
        int i = rs[g], e = rs[g + 1];
        for (; i + 8 <= e; i += 8) {
            int t0 = ed[i],     t1 = ed[i + 1], t2 = ed[i + 2], t3 = ed[i + 3];
            int t4 = ed[i + 4], t5 = ed[i + 5], t6 = ed[i + 6], t7 = ed[i + 7];
            ushort4 u0 = *(const ushort4*)(hwu + t0 * H + fb);
            ushort4 u1 = *(const ushort4*)(hwu + t1 * H + fb);
            ushort4 u2 = *(const ushort4*)(hwu + t2 * H + fb);
            ushort4 u3 = *(const ushort4*)(hwu + t3 * H + fb);
            ushort4 u4 = *(const ushort4*)(hwu + t4 * H + fb);
            ushort4 u5 = *(const ushort4*)(hwu + t5 * H + fb);
            ushort4 u6 = *(const ushort4*)(hwu + t6 * H + fb);
            ushort4 u7 = *(const ushort4*)(hwu + t7 * H + fb);
            accA.x += bfu2f(u0.x); accA.y += bfu2f(u0.y); accA.z += bfu2f(u0.z); accA.w += bfu2f(u0.w);
            accB.x += bfu2f(u1.x); accB.y += bfu2f(u1.y); accB.z += bfu2f(u1.z); accB.w += bfu2f(u1.w);
            accA.x += bfu2f(u2.x); accA.y += bfu2f(u2.y); accA.z += bfu2f(u2.z); accA.w += bfu2f(u2.w);
            accB.x += bfu2f(u3.x); accB.y += bfu2f(u3.y); accB.z += bfu2f(u3.z); accB.w += bfu2f(u3.w);
            accA.x += bfu2f(u4.x); accA.y += bfu2f(u4.y); accA.z += bfu2f(u4.z); accA.w += bfu2f(u4.w);
            accB.x += bfu2f(u5.x); accB.y += bfu2f(u5.y); accB.z += bfu2f(u5.z); accB.w += bfu2f(u5.w);
            accA.x += bfu2f(u6.x); accA.y += bfu2f(u6.y); accA.z += bfu2f(u6.z); accA.w += bfu2f(u6.w);
            accB.x += bfu2f(u7.x); accB.y += bfu2f(u7.y); accB.z += bfu2f(u7.z); accB.w += bfu2f(u7.w);
        }
        for (; i < e; ++i) {
            ushort4 u = *(const ushort4*)(hwu + ed[i] * H + fb);
            accA.x += bfu2f(u.x); accA.y += bfu2f(u.y); accA.z += bfu2f(u.z); accA.w += bfu2f(u.w);
        }
    }

    // self-loop + bias + relu
    ushort4 us = *(const ushort4*)(hwu + (size_t)v * H + fb);
    float dv = dinv[v];
    float4 bv = *(const float4*)(bias + fb);
    float4 val;
    val.x = fmaxf((accA.x + accB.x + bfu2f(us.x)) * dv + bv.x, 0.f);
    val.y = fmaxf((accA.y + accB.y + bfu2f(us.y)) * dv + bv.y, 0.f);
    val.z = fmaxf((accA.z + accB.z + bfu2f(us.z)) * dv + bv.z, 0.f);
    val.w = fmaxf((accA.w + accB.w + bfu2f(us.w)) * dv + bv.w, 0.f);

    // jk running max
    float4* jkp = (float4*)(jk + (size_t)v * H + fb);
    float4 jv = val;
    if (!first) {
        float4 jo = *jkp;
        jv.x = fmaxf(jo.x, val.x); jv.y = fmaxf(jo.y, val.y);
        jv.z = fmaxf(jo.z, val.z); jv.w = fmaxf(jo.w, val.w);
    }
    if (!last) {
        *jkp = jv;
    } else {
        // fused FC: out[v] = dot(jv_all16, fc_w) + fc_b
        float4 wv = *(const float4*)(fcw + fb);
        float partial = jv.x * wv.x + jv.y * wv.y + jv.z * wv.z + jv.w * wv.w;
        partial += __shfl_xor(partial, 1, 4);
        partial += __shfl_xor(partial, 2, 4);
        if (l == 0) out[v] = partial + fcb[0];
    }

    // fused next-layer transform: out[f'] = sum_k val_all[k] * W[k][f']
    if (has_next) {
        float4 o = make_float4(0.f, 0.f, 0.f, 0.f);
#pragma unroll
        for (int kq = 0; kq < 4; ++kq) {
            float4 vk;
            vk.x = __shfl(val.x, kq, 4);
            vk.y = __shfl(val.y, kq, 4);
            vk.z = __shfl(val.z, kq, 4);
            vk.w = __shfl(val.w, kq, 4);
            float4 w0 = *(const float4*)(Wl + (4 * kq + 0) * H + fb);
            float4 w1 = *(const float4*)(Wl + (4 * kq + 1) * H + fb);
            float4 w2 = *(const float4*)(Wl + (4 * kq + 2) * H + fb);
            float4 w3 = *(const float4*)(Wl + (4 * kq + 3) * H + fb);
            o.x += vk.x * w0.x + vk.y * w1.x + vk.z * w2.x + vk.w * w3.x;
            o.y += vk.x * w0.y + vk.y * w1.y + vk.z * w2.y + vk.w * w3.y;
            o.z += vk.x * w0.z + vk.y * w1.z + vk.z * w2.z + vk.w * w3.z;
            o.w += vk.x * w0.w + vk.y * w1.w + vk.z * w2.w + vk.w * w3.w;
        }
        ushort4 ob;
        ob.x = (unsigned short)(__bfloat16_as_ushort(__float2bfloat16(o.x * dv)));
        ob.y = (unsigned short)(__bfloat16_as_ushort(__float2bfloat16(o.y * dv)));
        ob.z = (unsigned short)(__bfloat16_as_ushort(__float2bfloat16(o.z * dv)));
        ob.w = (unsigned short)(__bfloat16_as_ushort(__float2bfloat16(o.w * dv)));
        *(ushort4*)((unsigned short*)hw_next + (size_t)v * H + fb) = ob;
    }
}

extern "C" void kernel_launch(void* const* d_in, const int* in_sizes, int n_in,
                              void* d_out, int out_size, void* d_ws, size_t ws_size,
                              hipStream_t stream) {
    const float* x    = (const float*)d_in[0];
    const void*  eidx = d_in[1];
    const float* W0   = (const float*)d_in[2];
    const float* Ws   = (const float*)d_in[3];
    const float* bs   = (const float*)d_in[4];
    const float* fc_w = (const float*)d_in[5];
    const float* fc_b = (const float*)d_in[6];

    int n = in_sizes[0] / F_IN;        // 100000
    int E = in_sizes[1] / 2;           // 3200000
    int L = in_sizes[4] / H;           // 10

    // workspace carve-up
    char* w = (char*)d_ws;
    size_t off = 0;
    int* rowstart    = (int*)(w + off); off += align256((size_t)(n + 1) * 4);
    float* dinv      = (float*)(w + off); off += align256((size_t)n * 4);
    int* bucketcnt   = (int*)(w + off); off += align256(512 * 4);
    int* bucketbase  = (int*)(w + off); off += align256(513 * 4);
    int* gcur        = (int*)(w + off); off += align256(512 * 4);
    int* flag64      = (int*)(w + off); off += align256(256);
    unsigned* stg    = (unsigned*)(w + off); off += align256((size_t)E * 4);
    int* ed          = (int*)(w + off); off += align256((size_t)E * 4 + 64);
    __hip_bfloat16* hwA = (__hip_bfloat16*)(w + off); off += align256((size_t)n * H * 2);
    __hip_bfloat16* hwB = (__hip_bfloat16*)(w + off); off += align256((size_t)n * H * 2);
    float* jk        = (float*)(w + off); off += align256((size_t)n * H * 4);

    int NB = (n + 255) / 256;          // 391 buckets of 256 nodes

    hipMemsetAsync(bucketcnt, 0, 512 * 4, stream);
    detect_kernel<<<1, 256, 0, stream>>>((const int*)eidx, flag64);
    bcount_kernel<<<512, 256, 0, stream>>>(eidx, E, flag64, n, bucketcnt);
    bscan_kernel<<<1, 512, 0, stream>>>(bucketcnt, NB, E, gcur, bucketbase);
    int SG = (E + 4095) / 4096;        // chunk <= 4096 <= SCH
    stage_kernel<<<SG, 256, 0, stream>>>(eidx, E, flag64, n, gcur, stg);
    fine_kernel<<<NB, 256, 0, stream>>>(stg, bucketbase, n, E, ed, rowstart, dinv);

    int ngrid = (n + NPB - 1) / NPB;   // 6250
    t0_kernel<<<ngrid, 256, 0, stream>>>(x, W0, dinv, hwA, n);

    __hip_bfloat16* cur = hwA;
    __hip_bfloat16* nxt = hwB;
    int agrid = (n + 63) / 64;         // 1563
    for (int l = 0; l < L; ++l) {
        const float* bias  = bs + (size_t)l * H;
        const float* Wnext = (l < L - 1) ? (Ws + (size_t)l * H * H) : nullptr;
        agg_kernel<<<agrid, 256, 0, stream>>>(ed, rowstart, dinv, cur, bias, Wnext,
                                              jk, nxt, fc_w, fc_b, (float*)d_out,
                                              n, (l == 0) ? 1 : 0,
                                              (l < L - 1) ? 1 : 0,
                                              (l == L - 1) ? 1 : 0);
        __hip_bfloat16* t = cur; cur = nxt; nxt = t;
    }
}